// Round 1
// baseline (287.154 us; speedup 1.0000x reference)
//
#include <hip/hip_runtime.h>
#include <hip/hip_bf16.h>

// out[b,i,d] = x[b,i,0] * W[i,d] + b[i,d]
// B=128, N=1024, D=512, fp32. Pure write-bandwidth-bound broadcast FMA.
//
// Layout: flat output index grouped as float4: idx4 in [0, B*N*D/4).
//   d4  = idx4 % (D/4)      (consecutive lanes -> consecutive d: coalesced)
//   row = idx4 / (D/4)      (row = b*N + i)
//   i   = row % N
// x[row] is a broadcast load (same addr across 128 consecutive threads ->
// cache broadcast); W/b float4 loads hit L2/L3 after first batch touches them.

constexpr int kB = 128;
constexpr int kN = 1024;
constexpr int kD = 512;
constexpr int kD4 = kD / 4;          // 128, power of two
constexpr int kTotal4 = kB * kN * kD4; // 16,777,216

__global__ __launch_bounds__(256) void bcast_fma_kernel(
    const float* __restrict__ x,      // [B*N]
    const float4* __restrict__ W,     // [N*D/4]
    const float4* __restrict__ bias,  // [N*D/4]
    float4* __restrict__ out)         // [B*N*D/4]
{
    int idx = blockIdx.x * blockDim.x + threadIdx.x;  // < kTotal4, exact grid
    int d4  = idx & (kD4 - 1);
    int row = idx >> 7;               // idx / kD4
    int i   = row & (kN - 1);         // row % N

    float  xv = x[row];
    float4 wv = W[i * kD4 + d4];
    float4 bv = bias[i * kD4 + d4];

    float4 o;
    o.x = fmaf(xv, wv.x, bv.x);
    o.y = fmaf(xv, wv.y, bv.y);
    o.z = fmaf(xv, wv.z, bv.z);
    o.w = fmaf(xv, wv.w, bv.w);
    out[idx] = o;
}

extern "C" void kernel_launch(void* const* d_in, const int* in_sizes, int n_in,
                              void* d_out, int out_size, void* d_ws, size_t ws_size,
                              hipStream_t stream) {
    const float*  x    = (const float*)d_in[0];   // [B,N,1]
    const float4* W    = (const float4*)d_in[1];  // [N,D]
    const float4* bias = (const float4*)d_in[2];  // [N,D]
    float4* out = (float4*)d_out;

    constexpr int kBlock = 256;
    constexpr int kGrid  = kTotal4 / kBlock;      // 65536, exact
    bcast_fma_kernel<<<kGrid, kBlock, 0, stream>>>(x, W, bias, out);
}

// Round 2
// 279.389 us; speedup vs baseline: 1.0278x; 1.0278x over previous
//
#include <hip/hip_runtime.h>
#include <hip/hip_bf16.h>

// out[b,i,d] = x[b,i,0] * W[i,d] + b[i,d]
// B=128, N=1024, D=512, fp32. Write-BW-bound broadcast FMA.
//
// Structure: one 64-lane wave per row (row = b*N + i). A row is 512 floats =
// 128 float4; each lane handles d4=lane and d4=lane+64 (16 B/lane per access,
// fully coalesced 1 KiB/wave transactions). x[row] is wave-uniform. Output
// uses nontemporal stores so the 256 MiB streaming write doesn't evict the
// 4 MiB W+bias working set from per-XCD L2.

constexpr int kB  = 128;
constexpr int kN  = 1024;
constexpr int kD4 = 512 / 4;           // 128 float4 per row
constexpr int kRows = kB * kN;         // 131072

typedef float v4f __attribute__((ext_vector_type(4)));

__global__ __launch_bounds__(256) void bcast_fma_kernel(
    const float* __restrict__ x,       // [B*N]
    const v4f*   __restrict__ W,       // [N*D4]
    const v4f*   __restrict__ bias,    // [N*D4]
    v4f*         __restrict__ out)     // [B*N*D4]
{
    const int wave = threadIdx.x >> 6;             // 0..3
    const int lane = threadIdx.x & 63;
    const int row  = (blockIdx.x << 2) + wave;     // < kRows, exact grid
    const int i    = row & (kN - 1);

    const float xv = x[row];                       // wave-uniform broadcast

    const int wb = i * kD4;
    const int ob = row * kD4;

    v4f w0 = W[wb + lane];
    v4f w1 = W[wb + lane + 64];
    v4f b0 = bias[wb + lane];
    v4f b1 = bias[wb + lane + 64];

    v4f o0, o1;
    o0.x = fmaf(xv, w0.x, b0.x);
    o0.y = fmaf(xv, w0.y, b0.y);
    o0.z = fmaf(xv, w0.z, b0.z);
    o0.w = fmaf(xv, w0.w, b0.w);
    o1.x = fmaf(xv, w1.x, b1.x);
    o1.y = fmaf(xv, w1.y, b1.y);
    o1.z = fmaf(xv, w1.z, b1.z);
    o1.w = fmaf(xv, w1.w, b1.w);

    __builtin_nontemporal_store(o0, &out[ob + lane]);
    __builtin_nontemporal_store(o1, &out[ob + lane + 64]);
}

extern "C" void kernel_launch(void* const* d_in, const int* in_sizes, int n_in,
                              void* d_out, int out_size, void* d_ws, size_t ws_size,
                              hipStream_t stream) {
    const float* x    = (const float*)d_in[0];
    const v4f*   W    = (const v4f*)d_in[1];
    const v4f*   bias = (const v4f*)d_in[2];
    v4f*         out  = (v4f*)d_out;

    constexpr int kBlock = 256;                    // 4 waves = 4 rows/block
    constexpr int kGrid  = kRows / 4;              // 32768, exact
    bcast_fma_kernel<<<kGrid, kBlock, 0, stream>>>(x, W, bias, out);
}

// Round 3
// 268.959 us; speedup vs baseline: 1.0676x; 1.0388x over previous
//
#include <hip/hip_runtime.h>
#include <hip/hip_bf16.h>

// out[b,i,d] = x[b,i,0] * W[i,d] + b[i,d]
// B=128, N=1024, D=512, fp32. Write-BW-bound broadcast FMA.
//
// One wave owns row i for kBG=8 consecutive batches: W/bias row loaded ONCE
// into registers (w0,w1,b0,b1 -> 16 VGPRs), then 8 wave-uniform x loads and
// 16 nontemporal float4 stores (256 B/lane written per 64 B read). This makes
// the kernel ~pure-write (like the 6.4 TB/s fill kernel) instead of 1:1
// read:write. NT stores keep the 256 MiB stream from evicting W/bias in L2.

constexpr int kB   = 128;
constexpr int kN   = 1024;
constexpr int kD4  = 512 / 4;            // 128 float4 per row
constexpr int kBG  = 8;                  // batches per wave
constexpr int kRowStride4 = kN * kD4;    // float4 stride between batches

typedef float v4f __attribute__((ext_vector_type(4)));

__global__ __launch_bounds__(256) void bcast_fma_kernel(
    const float* __restrict__ x,       // [B*N]
    const v4f*   __restrict__ W,       // [N*D4]
    const v4f*   __restrict__ bias,    // [N*D4]
    v4f*         __restrict__ out)     // [B*N*D4]
{
    const int wave = threadIdx.x >> 6;              // 0..3
    const int lane = threadIdx.x & 63;
    const int w    = (blockIdx.x << 2) + wave;      // wave id, < kN * (kB/kBG)
    const int i    = w & (kN - 1);                  // row index
    const int bg   = w >> 10;                       // batch group, 0..15

    const int wb = i * kD4;
    const v4f w0 = W[wb + lane];
    const v4f w1 = W[wb + lane + 64];
    const v4f b0 = bias[wb + lane];
    const v4f b1 = bias[wb + lane + 64];

    // Wave-uniform x values for the 8 batches (issued up-front for ILP).
    float xv[kBG];
#pragma unroll
    for (int g = 0; g < kBG; ++g)
        xv[g] = x[(bg * kBG + g) * kN + i];

    // Output base for batch bg*kBG, row i.
    const long ob = (long)(bg * kBG) * kRowStride4 + (long)i * kD4 + lane;

#pragma unroll
    for (int g = 0; g < kBG; ++g) {
        const float xg = xv[g];
        v4f o0, o1;
        o0.x = fmaf(xg, w0.x, b0.x);
        o0.y = fmaf(xg, w0.y, b0.y);
        o0.z = fmaf(xg, w0.z, b0.z);
        o0.w = fmaf(xg, w0.w, b0.w);
        o1.x = fmaf(xg, w1.x, b1.x);
        o1.y = fmaf(xg, w1.y, b1.y);
        o1.z = fmaf(xg, w1.z, b1.z);
        o1.w = fmaf(xg, w1.w, b1.w);
        __builtin_nontemporal_store(o0, &out[ob + (long)g * kRowStride4]);
        __builtin_nontemporal_store(o1, &out[ob + (long)g * kRowStride4 + 64]);
    }
}

extern "C" void kernel_launch(void* const* d_in, const int* in_sizes, int n_in,
                              void* d_out, int out_size, void* d_ws, size_t ws_size,
                              hipStream_t stream) {
    const float* x    = (const float*)d_in[0];
    const v4f*   W    = (const v4f*)d_in[1];
    const v4f*   bias = (const v4f*)d_in[2];
    v4f*         out  = (v4f*)d_out;

    constexpr int kWaves = kN * (kB / kBG);        // 16384
    constexpr int kGrid  = kWaves / 4;             // 4096 blocks of 256
    bcast_fma_kernel<<<kGrid, 256, 0, stream>>>(x, W, bias, out);
}